// Round 2
// baseline (923.348 us; speedup 1.0000x reference)
//
#include <hip/hip_runtime.h>
#include <hip/hip_fp16.h>

// Problem constants: B=64, N=256, F_IN=768, F_OUT=256
#define NB    64
#define NN    256
#define FIN   768
#define FOUT  256

typedef _Float16 half8v __attribute__((ext_vector_type(8)));
typedef float    float4v __attribute__((ext_vector_type(4)));

__device__ inline __half2 u2h2(unsigned int u){
  union { unsigned int u; __half2 h; } cv; cv.u = u; return cv.h;
}
__device__ inline unsigned int h22u(__half2 h){
  union { __half2 h; unsigned int u; } cv; cv.h = h; return cv.u;
}

// f32 -> fp8 e4m3 (OCP, RNE) single value
__device__ inline unsigned char enc8(float v){
#if __has_builtin(__builtin_amdgcn_cvt_pk_fp8_f32)
  return (unsigned char)(__builtin_amdgcn_cvt_pk_fp8_f32(v, v, 0, false) & 0xFF);
#else
  float best = 1e30f; unsigned char bc = 0;
  for (int c = 0; c < 256; c++){
    if ((c & 0x7F) == 0x7F) continue;            // NaN codes
    int e = (c >> 3) & 15, mnt = c & 7;
    float mag = e ? ldexpf(1.f + mnt*0.125f, e-7) : ldexpf(mnt*0.125f, -6);
    float d = (c >> 7) ? -mag : mag;
    float err = fabsf(v - d);
    if (err < best){ best = err; bc = (unsigned char)c; }
  }
  return bc;
#endif
}
// f32 pair -> 2 fp8 bytes packed in low u16
__device__ inline unsigned short enc8pair(float a, float b){
#if __has_builtin(__builtin_amdgcn_cvt_pk_fp8_f32)
  return (unsigned short)(__builtin_amdgcn_cvt_pk_fp8_f32(a, b, 0, false) & 0xFFFF);
#else
  return (unsigned short)enc8(a) | ((unsigned short)enc8(b) << 8);
#endif
}

__device__ inline float4v mfma_fp8(long long a, long long b, float4v c){
  return __builtin_amdgcn_mfma_f32_16x16x32_fp8_fp8(a, b, c, 0, 0, 0);
}

// Swizzled fp8 weight layout for MFMA A-frags:
// off(o,k) = ((o>>4)*8 + (k>>5))*512 + ((k>>3)&3)*128 + (o&15)*8 + (k&7)

// ---------------------------------------------------------------------------
// prep: f16 conversions for the big x-side GEMMs.
// ---------------------------------------------------------------------------
__global__ __launch_bounds__(256) void prep_kernel(
    const float* __restrict__ emb_W, const float* __restrict__ ioux_W,
    const float* __restrict__ ioux_b, const float* __restrict__ coux_W,
    const float* __restrict__ coux_b,
    _Float16* __restrict__ embW16, _Float16* __restrict__ Wcat16,
    float* __restrict__ biascat)
{
  int idx = blockIdx.x*256 + threadIdx.x;
  if (idx < 196608) { embW16[idx] = (_Float16)emb_W[idx]; return; }
  idx -= 196608;
  if (idx < 196608) {
    int o = idx >> 8, k = idx & 255;
    float v = (o < 512) ? ioux_W[o*256 + k] : coux_W[(o-512)*256 + k];
    Wcat16[idx] = (_Float16)v; return;
  }
  idx -= 196608;
  if (idx < 768) { biascat[idx] = (idx < 512) ? ioux_b[idx] : coux_b[idx-512]; return; }
}

// ---------------------------------------------------------------------------
// quant: per-output-row fp8 e4m3 quantization of iouh_W / couh_W in the
// MFMA swizzled layout. invrs[o] = 1/(rowscale*16).
// ---------------------------------------------------------------------------
__global__ __launch_bounds__(256) void quant_kernel(
    const float* __restrict__ iouh_W, const float* __restrict__ couh_W,
    unsigned char* __restrict__ iouh8, unsigned char* __restrict__ couh8,
    float* __restrict__ invrs_iou, float* __restrict__ invrs_cou)
{
  const int row = blockIdx.x;       // 0..767
  const int t   = threadIdx.x;      // 0..255 (k index)
  const bool is_iou = (row < 512);
  const int rl = is_iou ? row : row - 512;
  const float w = is_iou ? iouh_W[(size_t)rl*256 + t] : couh_W[(size_t)rl*256 + t];

  __shared__ float sm[256];
  sm[t] = fabsf(w);
  __syncthreads();
  for (int s = 128; s > 0; s >>= 1){
    if (t < s) sm[t] = fmaxf(sm[t], sm[t+s]);
    __syncthreads();
  }
  const float mx = sm[0];
  const float rs = (mx > 1e-20f) ? (240.0f / mx) : 1.0f;
  const unsigned char byte = enc8(w * rs);
  const int off = ((rl>>4)*8 + (t>>5))*512 + ((t>>3)&3)*128 + (rl&15)*8 + (t&7);
  if (is_iou) iouh8[off] = byte; else couh8[off] = byte;
  if (t == 0){
    const float inv = 1.0f / (rs * 16.0f);
    if (is_iou) invrs_iou[rl] = inv; else invrs_cou[rl] = inv;
  }
}

// ---------------------------------------------------------------------------
// degmask: per (b,i): row degree inverse + transposed adjacency bitmask.
// ---------------------------------------------------------------------------
__global__ __launch_bounds__(256) void degmask_kernel(
    const float* __restrict__ adj, unsigned int* __restrict__ maskw,
    float* __restrict__ dinv)
{
  const int b = blockIdx.x, i = threadIdx.x;
  const float* ab = adj + (size_t)b*NN*NN;
  #pragma unroll
  for (int q = 0; q < 8; q++){
    unsigned int wq = 0;
    for (int jj = 0; jj < 32; jj++){
      float v = ab[(size_t)(q*32+jj)*NN + i];
      wq |= (v != 0.0f) ? (1u << jj) : 0u;
    }
    maskw[((size_t)b*NN + i)*8 + q] = wq;
  }
  float s = 0.f;
  const float4* rp = (const float4*)(ab + (size_t)i*NN);
  for (int j = 0; j < NN/4; j++){ float4 v = rp[j]; s += v.x + v.y + v.z + v.w; }
  dinv[b*NN + i] = (s != 0.f) ? 1.0f/s : 0.0f;
}

// ---------------------------------------------------------------------------
// GEMM (unchanged, validated): C = A @ Bw^T (+bias), C f16.
// ---------------------------------------------------------------------------
template<int AF32>
__global__ __launch_bounds__(256) void gemm16_kernel(
    const void* __restrict__ Aq, const _Float16* __restrict__ Bw,
    _Float16* __restrict__ Cout, const float* __restrict__ bias,
    int M, int N, int K, int ldc)
{
  const int wave = threadIdx.x >> 6;
  const int lane = threadIdx.x & 63;
  const int m0 = (blockIdx.x*4 + wave)*16;
  const int n0 = blockIdx.y*64;
  const int mrow = m0 + (lane & 15);
  const int kgrp = lane >> 4;
  float4v acc[4];
  #pragma unroll
  for (int nt = 0; nt < 4; nt++) acc[nt] = (float4v){0.f,0.f,0.f,0.f};

  for (int k0 = 0; k0 < K; k0 += 32){
    const int ka = k0 + kgrp*8;
    half8v af;
    if (AF32){
      const float* A = (const float*)Aq;
      const float4* ap = (const float4*)(A + (size_t)mrow*K + ka);
      float4 a0 = ap[0], a1 = ap[1];
      af[0]=(_Float16)a0.x; af[1]=(_Float16)a0.y; af[2]=(_Float16)a0.z; af[3]=(_Float16)a0.w;
      af[4]=(_Float16)a1.x; af[5]=(_Float16)a1.y; af[6]=(_Float16)a1.z; af[7]=(_Float16)a1.w;
    } else {
      const _Float16* A = (const _Float16*)Aq;
      af = *(const half8v*)(A + (size_t)mrow*K + ka);
    }
    #pragma unroll
    for (int nt = 0; nt < 4; nt++){
      const int ncol = n0 + nt*16 + (lane & 15);
      half8v bf = *(const half8v*)(Bw + (size_t)ncol*K + ka);
      acc[nt] = __builtin_amdgcn_mfma_f32_16x16x32_f16(af, bf, acc[nt], 0, 0, 0);
    }
  }
  #pragma unroll
  for (int nt = 0; nt < 4; nt++){
    const int ncol = n0 + nt*16 + (lane & 15);
    const float bv = bias ? bias[ncol] : 0.f;
    #pragma unroll
    for (int r = 0; r < 4; r++){
      const int orow = m0 + (lane>>4)*4 + r;
      Cout[(size_t)orow*ldc + ncol] = (_Float16)(acc[nt][r] + bv);
    }
  }
}

// ---------------------------------------------------------------------------
// scan: one block per batch element; 1024 threads = 16 waves (4/SIMD).
// R9 (this round, blind — infra down 2 rounds): fuse aggregation + reduce.
// Old org: wave w summed rows [16w,16w+16) over all 256 features -> cross-wave
// partials in LDS (sh_part 8KB round-trip) + separate reduce phase + barrier.
// New org: wave w sums ALL 256 rows over its OWN 16-feature slice
// [16w,16w+16): lane = (jrow 0..15) x (fq 0..3); 16 steps of 16 rows; in-wave
// shfl_xor butterfly over jrow lanes; lanes jrow==0 write xp32/xp8 directly.
//  - barriers/iter 4 -> 3; sh_part removed (-16KB LDS traffic/iter).
//  - sh_hc gets XOR swizzle byte^=((row&7)<<4) at ALL 3 access sites
//    (staging write, h_new write, aggregation read) -> 2-way banks (free).
//  - per-lane mask predication replaces wave-uniform row skip (same BW skip).
// LDS map (dynamic, 134656 B):
//   [0)       Hc f16 [256][256] swizzled  131072
//   [131072)  xp32 (256 f32)       1024
//   [132096)  xp8  (256 B)          256
//   [132352)  p8   (256 B)          256
//   [132608)  z    (256 f32)       1024
//   [133632)  pm   (256 f32)       1024
// ---------------------------------------------------------------------------
#define SCAN_LDS 134656

__global__ __launch_bounds__(1024)
void scan_kernel(
    const _Float16* __restrict__ Hc,    // [B*N][256] f16 = h_e (read once)
    const _Float16* __restrict__ OUTX,  // [B*N][768] f16: [iou_x ; cou_x]
    const unsigned char* __restrict__ iouh8,  // swizzled fp8 [512][256]
    const unsigned char* __restrict__ couh8,  // swizzled fp8 [256][256]
    const float* __restrict__ invrs_iou,      // [512]
    const float* __restrict__ invrs_cou,      // [256]
    const float* __restrict__ dinv,     // [B*N]
    const unsigned int* __restrict__ maskw, // [B*N][8] (+pad)
    const float* __restrict__ iouh_b,   // [512]
    const float* __restrict__ couh_b,   // [256]
    const float* __restrict__ fc_W,     // [2][256]
    const float* __restrict__ fc_b,     // [2]
    float* __restrict__ out)            // [B][2]
{
  const int b    = blockIdx.x;
  const int t    = threadIdx.x;        // 0..1023
  const int wave = t >> 6;             // 0..15
  const int lane = t & 63;
  const int q    = lane >> 4;          // k-octet within MFMA frags
  const int r    = lane & 15;          // row within MFMA tile

  extern __shared__ __align__(16) char smem[];
  float*         sh_xp32 = (float*)(smem + 131072);
  unsigned char* sh_xp8  = (unsigned char*)(smem + 132096);
  unsigned char* sh_p8   = (unsigned char*)(smem + 132352);
  float*         sh_z    = (float*)(smem + 132608);
  float*         sh_pm   = (float*)(smem + 133632);

  // ---- stage h_e into LDS Hc (XOR-swizzled rows): 131072 B = 8192 uint4 ----
  {
    const uint4* src = (const uint4*)(Hc + (size_t)b*NN*FOUT);
    #pragma unroll
    for (int k = 0; k < 8; k++){
      const int idx = k*1024 + t;              // uint4 index; 32 per row
      const int row = idx >> 5;
      const int dstb = (idx << 4) ^ ((row & 7) << 4);
      *(uint4*)(smem + dstb) = src[idx];
    }
  }

  // ---- weights into registers (48 dwords/thread, loop-invariant) ----
  long long ifrag[2][8];
  #pragma unroll
  for (int tt = 0; tt < 2; tt++)
    #pragma unroll
    for (int kc = 0; kc < 8; kc++)
      ifrag[tt][kc] = *(const long long*)(iouh8 + (size_t)(((2*wave+tt)*8 + kc)*512) + q*128 + r*8);
  long long cfrag[8];
  #pragma unroll
  for (int kc = 0; kc < 8; kc++)
    cfrag[kc] = *(const long long*)(couh8 + (size_t)((wave*8 + kc)*512) + q*128 + r*8);

  // ---- per-lane output assignments (loop-invariant) ----
  // gate lane (r<8): o_iou = 32w + ((r>>2)&1)*16 + q*4 + (r&3), one sigmoid.
  // update lane (r<4): o_upd = 16w + q*4 + r, one tanh.
  const int o_iou = 32*wave + ((r>>2)&1)*16 + q*4 + (r&3);   // < 512 always
  const int o_upd = 16*wave + q*4 + (r&3);                   // < 256 always
  const float biou_l = iouh_b[o_iou];
  const float invi_l = invrs_iou[o_iou];
  const float bcou_l = couh_b[o_upd];
  const float invc_l = invrs_cou[o_upd];
  float pmax = -1e30f;

  // ---- aggregation lane mapping (loop-invariant) ----
  const int fq   = lane & 3;           // feature quad within wave's 16-feat slice
  const int jrow = lane >> 2;          // 0..15: row-within-group in flight
  const int blo  = jrow;               // mask bit position, even group
  const int bhi  = 16 + jrow;          // mask bit position, odd group
  // swizzled byte offset within a row for this lane's uint2
  const int agg_fbyte = ((wave << 5) + (fq << 3)) ^ ((jrow & 7) << 4);
  const char* aggp = (const char*)smem + (size_t)jrow*512 + agg_fbyte;
  const int f0i = wave*16 + fq*4;      // first of this lane's 4 features

  // ---- adjacency-column mask (8 words) prefetch ----
  uint4 mca = *(const uint4*)(maskw + ((size_t)b*NN)*8);
  uint4 mcb = *(const uint4*)(maskw + ((size_t)b*NN)*8 + 4);
  __syncthreads();   // cover LDS staging

  #pragma unroll 1
  for (int i = 0; i < NN; i++){
    const size_t row = (size_t)b*NN + i;

    const uint4 mna = *(const uint4*)(maskw + (row+1)*8);
    const uint4 mnb = *(const uint4*)(maskw + (row+1)*8 + 4);
    // per-lane OUTX operands (HBM; used ~1000+ cyc later — latency covered)
    const float oxi = (float)OUTX[row*768 + o_iou];
    const float oxc = (float)OUTX[row*768 + 512 + o_upd];
    const float dv  = dinv[row];

    // ---- fused aggregation: 16 steps x 16 rows, per-lane mask predication
    __half2 a0 = __floats2half2_rn(0.f, 0.f), a1 = a0;   // even steps
    __half2 b0 = a0, b1 = a0;                            // odd steps
#define AGG_STEP(ss, WRD) { \
      uint2 d = make_uint2(0u, 0u); \
      if ((WRD >> (((ss) & 1) ? bhi : blo)) & 1u) \
        d = *(const uint2*)(aggp + (ss)*8192); \
      if ((ss) & 1) { b0 = __hadd2(b0, u2h2(d.x)); b1 = __hadd2(b1, u2h2(d.y)); } \
      else          { a0 = __hadd2(a0, u2h2(d.x)); a1 = __hadd2(a1, u2h2(d.y)); } }
    AGG_STEP(0,  mca.x) AGG_STEP(1,  mca.x)
    AGG_STEP(2,  mca.y) AGG_STEP(3,  mca.y)
    AGG_STEP(4,  mca.z) AGG_STEP(5,  mca.z)
    AGG_STEP(6,  mca.w) AGG_STEP(7,  mca.w)
    AGG_STEP(8,  mcb.x) AGG_STEP(9,  mcb.x)
    AGG_STEP(10, mcb.y) AGG_STEP(11, mcb.y)
    AGG_STEP(12, mcb.z) AGG_STEP(13, mcb.z)
    AGG_STEP(14, mcb.w) AGG_STEP(15, mcb.w)
#undef AGG_STEP
    a0 = __hadd2(a0, b0); a1 = __hadd2(a1, b1);
    mca = mna; mcb = mnb;

    // ---- in-wave butterfly over jrow lanes (stride 4), f32 ----
    float f0 = __low2float(a0), f1 = __high2float(a0);
    float f2 = __low2float(a1), f3 = __high2float(a1);
    #pragma unroll
    for (int off = 4; off < 64; off <<= 1){
      f0 += __shfl_xor(f0, off, 64);
      f1 += __shfl_xor(f1, off, 64);
      f2 += __shfl_xor(f2, off, 64);
      f3 += __shfl_xor(f3, off, 64);
    }
    if (jrow == 0){   // lanes 0..3 of each wave: 4 features each
      const float s0 = f0*dv, s1 = f1*dv, s2 = f2*dv, s3 = f3*dv;
      float4 xo; xo.x = s0; xo.y = s1; xo.z = s2; xo.w = s3;
      *(float4*)&sh_xp32[f0i] = xo;
      const unsigned int pk = (unsigned int)enc8pair(s0*16.f, s1*16.f)
                            | ((unsigned int)enc8pair(s2*16.f, s3*16.f) << 16);
      *(unsigned int*)(sh_xp8 + f0i) = pk;
    }
    __syncthreads();                                    // B2

    // ---- iou matvec via fp8 MFMA (A-frags in regs) + fused gates ----
    {
      float4v iacc[2];
      iacc[0] = (float4v){0.f,0.f,0.f,0.f};
      iacc[1] = iacc[0];
      #pragma unroll
      for (int kc = 0; kc < 8; kc++){
        const long long bfr = *(const long long*)(sh_xp8 + kc*32 + q*8);
        iacc[0] = mfma_fp8(ifrag[0][kc], bfr, iacc[0]);
        iacc[1] = mfma_fp8(ifrag[1][kc], bfr, iacc[1]);
      }
      if (r < 8){
        // select this lane's output value from the replicated accumulators
        const float4v ia = (r < 4) ? iacc[0] : iacc[1];
        const int rr = r & 3;
        const float v01 = (rr == 0) ? ia[0] : ia[1];
        const float v23 = (rr == 2) ? ia[2] : ia[3];
        const float dval = (rr < 2) ? v01 : v23;
        const float iouv = dval*invi_l + oxi + biou_l;
        const float sg = 1.f / (1.f + __expf(-iouv));
        if (o_iou < 256) sh_p8[o_iou] = enc8(sg * sh_xp32[o_iou] * 16.f);
        else             sh_z[o_iou - 256] = sg;
      }
    }
    __syncthreads();                                    // B3

    // ---- cou matvec (A-frags in regs) + lane-split fused update ----
    {
      float4v cacc = (float4v){0.f,0.f,0.f,0.f};
      #pragma unroll
      for (int kc = 0; kc < 8; kc++){
        const long long bfr = *(const long long*)(sh_p8 + kc*32 + q*8);
        cacc = mfma_fp8(cfrag[kc], bfr, cacc);
      }
      if (r < 4){
        const float c01 = (r == 0) ? cacc[0] : cacc[1];
        const float c23 = (r == 2) ? cacc[2] : cacc[3];
        const float cd  = (r < 2) ? c01 : c23;
        const float v   = cd*invc_l + oxc + bcou_l;
        const float hcv = tanhf(v);
        const float z   = sh_z[o_upd];
        const float xpv = sh_xp32[o_upd];
        const float hn  = z*xpv + (1.f - z)*hcv;
        pmax = fmaxf(pmax, hn);
        const int updb = (i*512 + o_upd*2) ^ ((i & 7) << 4);  // swizzled
        *(_Float16*)(smem + updb) = (_Float16)hn;
      }
    }
    __syncthreads();                                    // B4 (hc/p8/xp reuse)
  }

  // ---- epilogue: pooled max -> fc ----
  if (r < 4) sh_pm[o_upd] = pmax;
  __syncthreads();
  if (t < 128){
    const int c = t >> 6;   // 0 or 1
    float s = 0.f;
    #pragma unroll
    for (int qq = 0; qq < 4; qq++){
      const int f = (t & 63) + qq*64;
      s += fc_W[c*256 + f] * sh_pm[f];
    }
    #pragma unroll
    for (int off = 32; off > 0; off >>= 1) s += __shfl_xor(s, off, 64);
    if ((t & 63) == 0) out[b*2 + c] = s + fc_b[c];
  }
}

// ---------------------------------------------------------------------------
extern "C" void kernel_launch(void* const* d_in, const int* in_sizes, int n_in,
                              void* d_out, int out_size, void* d_ws, size_t ws_size,
                              hipStream_t stream)
{
  (void)in_sizes; (void)n_in; (void)out_size; (void)ws_size;
  const float* h      = (const float*)d_in[0];
  const float* adj    = (const float*)d_in[1];
  const float* emb_W  = (const float*)d_in[2];
  const float* ioux_W = (const float*)d_in[3];
  const float* ioux_b = (const float*)d_in[4];
  const float* iouh_W = (const float*)d_in[5];
  const float* iouh_b = (const float*)d_in[6];
  const float* coux_W = (const float*)d_in[7];
  const float* coux_b = (const float*)d_in[8];
  const float* couh_W = (const float*)d_in[9];
  const float* couh_b = (const float*)d_in[10];
  const float* fc_W   = (const float*)d_in[11];
  const float* fc_b   = (const float*)d_in[12];
  float* out = (float*)d_out;

  // ---- carve workspace (256B aligned chunks) ----
  size_t off = 0;
  char* base = (char*)d_ws;
  auto carve = [&](size_t bytes)->char* {
    off = (off + 255) & ~(size_t)255;
    char* p = base + off;
    off += bytes;
    return p;
  };
  _Float16* embW16 = (_Float16*)carve((size_t)256*768*2);
  _Float16* Wcat16 = (_Float16*)carve((size_t)768*256*2);
  float*    biascat= (float*)  carve((size_t)768*4);
  unsigned char* iouh8 = (unsigned char*)carve(131072);
  unsigned char* couh8 = (unsigned char*)carve(65536);
  float*    invrs_iou = (float*)carve(512*4);
  float*    invrs_cou = (float*)carve(256*4);
  float*    dinv   = (float*)  carve((size_t)NB*NN*4);
  unsigned int* maskw = (unsigned int*)carve((size_t)NB*NN*8*4 + 64); // +pad for prefetch
  _Float16* Hc     = (_Float16*)carve((size_t)NB*NN*FOUT*2);       // h_e
  _Float16* OUTX   = (_Float16*)carve((size_t)NB*NN*768*2);        // [iou_x ; cou_x]

  // raise dynamic LDS cap for the scan kernel (idempotent, non-stream op)
  hipFuncSetAttribute((const void*)scan_kernel,
                      hipFuncAttributeMaxDynamicSharedMemorySize, SCAN_LDS);

  // 1) f16 weight conversion for x-side GEMMs
  prep_kernel<<<dim3(1539), dim3(256), 0, stream>>>(
      emb_W, ioux_W, ioux_b, coux_W, coux_b, embW16, Wcat16, biascat);

  // 2) fp8 quantization of recurrent weights (swizzled for MFMA frags)
  quant_kernel<<<dim3(768), dim3(256), 0, stream>>>(
      iouh_W, couh_W, iouh8, couh8, invrs_iou, invrs_cou);

  // 3) degrees + adjacency column bitmasks
  degmask_kernel<<<dim3(NB), dim3(256), 0, stream>>>(adj, maskw, dinv);

  // 4) h_e = h @ emb_W^T
  gemm16_kernel<1><<<dim3(256, 4), dim3(256), 0, stream>>>(
      (const void*)h, embW16, Hc, nullptr, NB*NN, FOUT, FIN, FOUT);

  // 5) [iou_x ; cou_x] = h_e @ Wcat^T + biascat
  gemm16_kernel<0><<<dim3(256, 12), dim3(256), 0, stream>>>(
      (const void*)Hc, Wcat16, OUTX, biascat, NB*NN, 768, FOUT, 768);

  // 6) sequential tree scan (1024 threads; Hc in LDS, weights in VGPRs)
  scan_kernel<<<dim3(NB), dim3(1024), SCAN_LDS, stream>>>(
      Hc, OUTX, iouh8, couh8, invrs_iou, invrs_cou, dinv, maskw,
      iouh_b, couh_b, fc_W, fc_b, out);
}

// Round 3
// 752.908 us; speedup vs baseline: 1.2264x; 1.2264x over previous
//
#include <hip/hip_runtime.h>
#include <hip/hip_fp16.h>

// Problem constants: B=64, N=256, F_IN=768, F_OUT=256
#define NB    64
#define NN    256
#define FIN   768
#define FOUT  256

typedef _Float16 half8v __attribute__((ext_vector_type(8)));
typedef float    float4v __attribute__((ext_vector_type(4)));

// f32 -> fp8 e4m3 (OCP, RNE) single value
__device__ inline unsigned char enc8(float v){
#if __has_builtin(__builtin_amdgcn_cvt_pk_fp8_f32)
  return (unsigned char)(__builtin_amdgcn_cvt_pk_fp8_f32(v, v, 0, false) & 0xFF);
#else
  float best = 1e30f; unsigned char bc = 0;
  for (int c = 0; c < 256; c++){
    if ((c & 0x7F) == 0x7F) continue;            // NaN codes
    int e = (c >> 3) & 15, mnt = c & 7;
    float mag = e ? ldexpf(1.f + mnt*0.125f, e-7) : ldexpf(mnt*0.125f, -6);
    float d = (c >> 7) ? -mag : mag;
    float err = fabsf(v - d);
    if (err < best){ best = err; bc = (unsigned char)c; }
  }
  return bc;
#endif
}

__device__ inline float4v mfma_fp8(long long a, long long b, float4v c){
  return __builtin_amdgcn_mfma_f32_16x16x32_fp8_fp8(a, b, c, 0, 0, 0);
}

// Swizzled fp8 weight layout for MFMA A-frags:
// off(o,k) = ((o>>4)*8 + (k>>5))*512 + ((k>>3)&3)*128 + (o&15)*8 + (k&7)

// H^T LDS swizzle: spreads feature-stride-512B accesses across 8 bank granules.
// Must be applied identically at staging-write, h_new-write, B-frag-read.
#define SWZ(f) (((((f)&7) ^ (((f)>>3)&7))) << 4)

// ---------------------------------------------------------------------------
// prep: f16 conversions for the big x-side GEMMs.
// ---------------------------------------------------------------------------
__global__ __launch_bounds__(256) void prep_kernel(
    const float* __restrict__ emb_W, const float* __restrict__ ioux_W,
    const float* __restrict__ ioux_b, const float* __restrict__ coux_W,
    const float* __restrict__ coux_b,
    _Float16* __restrict__ embW16, _Float16* __restrict__ Wcat16,
    float* __restrict__ biascat)
{
  int idx = blockIdx.x*256 + threadIdx.x;
  if (idx < 196608) { embW16[idx] = (_Float16)emb_W[idx]; return; }
  idx -= 196608;
  if (idx < 196608) {
    int o = idx >> 8, k = idx & 255;
    float v = (o < 512) ? ioux_W[o*256 + k] : coux_W[(o-512)*256 + k];
    Wcat16[idx] = (_Float16)v; return;
  }
  idx -= 196608;
  if (idx < 768) { biascat[idx] = (idx < 512) ? ioux_b[idx] : coux_b[idx-512]; return; }
}

// ---------------------------------------------------------------------------
// quant: per-output-row fp8 e4m3 quantization of iouh_W / couh_W in the
// MFMA swizzled layout. invrs[o] = 1/(rowscale*16).
// ---------------------------------------------------------------------------
__global__ __launch_bounds__(256) void quant_kernel(
    const float* __restrict__ iouh_W, const float* __restrict__ couh_W,
    unsigned char* __restrict__ iouh8, unsigned char* __restrict__ couh8,
    float* __restrict__ invrs_iou, float* __restrict__ invrs_cou)
{
  const int row = blockIdx.x;       // 0..767
  const int t   = threadIdx.x;      // 0..255 (k index)
  const bool is_iou = (row < 512);
  const int rl = is_iou ? row : row - 512;
  const float w = is_iou ? iouh_W[(size_t)rl*256 + t] : couh_W[(size_t)rl*256 + t];

  __shared__ float sm[256];
  sm[t] = fabsf(w);
  __syncthreads();
  for (int s = 128; s > 0; s >>= 1){
    if (t < s) sm[t] = fmaxf(sm[t], sm[t+s]);
    __syncthreads();
  }
  const float mx = sm[0];
  const float rs = (mx > 1e-20f) ? (240.0f / mx) : 1.0f;
  const unsigned char byte = enc8(w * rs);
  const int off = ((rl>>4)*8 + (t>>5))*512 + ((t>>3)&3)*128 + (rl&15)*8 + (t&7);
  if (is_iou) iouh8[off] = byte; else couh8[off] = byte;
  if (t == 0){
    const float inv = 1.0f / (rs * 16.0f);
    if (is_iou) invrs_iou[rl] = inv; else invrs_cou[rl] = inv;
  }
}

// ---------------------------------------------------------------------------
// degmask: per (b,i): row degree inverse + transposed adjacency bitmask.
// ---------------------------------------------------------------------------
__global__ __launch_bounds__(256) void degmask_kernel(
    const float* __restrict__ adj, unsigned int* __restrict__ maskw,
    float* __restrict__ dinv)
{
  const int b = blockIdx.x, i = threadIdx.x;
  const float* ab = adj + (size_t)b*NN*NN;
  #pragma unroll
  for (int q = 0; q < 8; q++){
    unsigned int wq = 0;
    for (int jj = 0; jj < 32; jj++){
      float v = ab[(size_t)(q*32+jj)*NN + i];
      wq |= (v != 0.0f) ? (1u << jj) : 0u;
    }
    maskw[((size_t)b*NN + i)*8 + q] = wq;
  }
  float s = 0.f;
  const float4* rp = (const float4*)(ab + (size_t)i*NN);
  for (int j = 0; j < NN/4; j++){ float4 v = rp[j]; s += v.x + v.y + v.z + v.w; }
  dinv[b*NN + i] = (s != 0.f) ? 1.0f/s : 0.0f;
}

// ---------------------------------------------------------------------------
// GEMM (unchanged, validated): C = A @ Bw^T (+bias), C f16.
// ---------------------------------------------------------------------------
template<int AF32>
__global__ __launch_bounds__(256) void gemm16_kernel(
    const void* __restrict__ Aq, const _Float16* __restrict__ Bw,
    _Float16* __restrict__ Cout, const float* __restrict__ bias,
    int M, int N, int K, int ldc)
{
  const int wave = threadIdx.x >> 6;
  const int lane = threadIdx.x & 63;
  const int m0 = (blockIdx.x*4 + wave)*16;
  const int n0 = blockIdx.y*64;
  const int mrow = m0 + (lane & 15);
  const int kgrp = lane >> 4;
  float4v acc[4];
  #pragma unroll
  for (int nt = 0; nt < 4; nt++) acc[nt] = (float4v){0.f,0.f,0.f,0.f};

  for (int k0 = 0; k0 < K; k0 += 32){
    const int ka = k0 + kgrp*8;
    half8v af;
    if (AF32){
      const float* A = (const float*)Aq;
      const float4* ap = (const float4*)(A + (size_t)mrow*K + ka);
      float4 a0 = ap[0], a1 = ap[1];
      af[0]=(_Float16)a0.x; af[1]=(_Float16)a0.y; af[2]=(_Float16)a0.z; af[3]=(_Float16)a0.w;
      af[4]=(_Float16)a1.x; af[5]=(_Float16)a1.y; af[6]=(_Float16)a1.z; af[7]=(_Float16)a1.w;
    } else {
      const _Float16* A = (const _Float16*)Aq;
      af = *(const half8v*)(A + (size_t)mrow*K + ka);
    }
    #pragma unroll
    for (int nt = 0; nt < 4; nt++){
      const int ncol = n0 + nt*16 + (lane & 15);
      half8v bf = *(const half8v*)(Bw + (size_t)ncol*K + ka);
      acc[nt] = __builtin_amdgcn_mfma_f32_16x16x32_f16(af, bf, acc[nt], 0, 0, 0);
    }
  }
  #pragma unroll
  for (int nt = 0; nt < 4; nt++){
    const int ncol = n0 + nt*16 + (lane & 15);
    const float bv = bias ? bias[ncol] : 0.f;
    #pragma unroll
    for (int r = 0; r < 4; r++){
      const int orow = m0 + (lane>>4)*4 + r;
      Cout[(size_t)orow*ldc + ncol] = (_Float16)(acc[nt][r] + bv);
    }
  }
}

// ---------------------------------------------------------------------------
// scan: one block per batch element; 1024 threads = 16 waves (4/SIMD).
// R10: aggregation via f16 MFMA over H^T-in-LDS.
//   x_parent = adjcol^T @ H  ==  MFMA(A = adjcol replicated rows, B = H).
//   - H stored TRANSPOSED in LDS: H^T[feat][node] f16, byte ^ SWZ(feat).
//     B-frag per lane = 8 contiguous f16 along node dim (ds_read_b128,
//     conflict-free under SWZ).
//   - adjcol as f16 0/1 [2][256] double-buffered; built from maskw bit during
//     PREVIOUS iteration's update phase (t<256 lanes). A-frag reads are
//     broadcast (same addr across 16 lanes).
//   - MFMA output replicated over rows -> EVERY lane holds x_parent for its
//     feature f_agg = 16*wave + (lane&15). No butterfly, no hadd chain,
//     no mask predication. q==0 lanes write xp32, q==1 lanes write xp8.
//   - f32 MFMA accumulation (better numerics than old f16 hadd tree).
//   3 barriers/iter unchanged; iou/cou fp8-MFMA phases unchanged.
// LDS map (dynamic, 135680 B):
//   [0)       H^T f16 [256 feat][256 node] swizzled  131072
//   [131072)  xp32 (256 f32)       1024
//   [132096)  xp8  (256 B)          256
//   [132352)  p8   (256 B)          256
//   [132608)  z    (256 f32)       1024
//   [133632)  pm   (256 f32)       1024
//   [134656)  adj  f16 [2][256]    1024
// ---------------------------------------------------------------------------
#define SCAN_LDS 135680

__global__ __launch_bounds__(1024)
void scan_kernel(
    const _Float16* __restrict__ Hc,    // [B*N][256] f16 = h_e (read once)
    const _Float16* __restrict__ OUTX,  // [B*N][768] f16: [iou_x ; cou_x]
    const unsigned char* __restrict__ iouh8,  // swizzled fp8 [512][256]
    const unsigned char* __restrict__ couh8,  // swizzled fp8 [256][256]
    const float* __restrict__ invrs_iou,      // [512]
    const float* __restrict__ invrs_cou,      // [256]
    const float* __restrict__ dinv,     // [B*N]
    const unsigned int* __restrict__ maskw, // [B*N][8] (+pad)
    const float* __restrict__ iouh_b,   // [512]
    const float* __restrict__ couh_b,   // [256]
    const float* __restrict__ fc_W,     // [2][256]
    const float* __restrict__ fc_b,     // [2]
    float* __restrict__ out)            // [B][2]
{
  const int b    = blockIdx.x;
  const int t    = threadIdx.x;        // 0..1023
  const int wave = t >> 6;             // 0..15
  const int lane = t & 63;
  const int q    = lane >> 4;          // k-octet within MFMA frags
  const int r    = lane & 15;          // row within MFMA tile

  extern __shared__ __align__(16) char smem[];
  float*         sh_xp32 = (float*)(smem + 131072);
  unsigned char* sh_xp8  = (unsigned char*)(smem + 132096);
  unsigned char* sh_p8   = (unsigned char*)(smem + 132352);
  float*         sh_z    = (float*)(smem + 132608);
  float*         sh_pm   = (float*)(smem + 133632);
  _Float16*      sh_adj  = (_Float16*)(smem + 134656);   // [2][256]

  // ---- stage h_e into LDS as H^T[feat][node], swizzled ----
  // thread t: feat block fb=(t&31)*8, node block n0=(t>>5)*8; 8x8 register
  // transpose; writes are b128 (8 nodes contiguous), banks spread by SWZ.
  {
    const int fb = (t & 31) * 8;
    const int n0 = (t >> 5) * 8;
    const _Float16* src = Hc + (size_t)b*NN*FOUT;
    uint4 u[8];
    #pragma unroll
    for (int j = 0; j < 8; j++)
      u[j] = *(const uint4*)(src + (size_t)(n0 + j)*FOUT + fb);
    #pragma unroll
    for (int e = 0; e < 8; e++){
      half8v v;
      #pragma unroll
      for (int j = 0; j < 8; j++) v[j] = ((const _Float16*)&u[j])[e];
      const int f = fb + e;
      *(half8v*)(smem + (((f<<9) + (n0<<1)) ^ SWZ(f))) = v;
    }
  }

  // ---- weights into registers (48 dwords/thread, loop-invariant) ----
  long long ifrag[2][8];
  #pragma unroll
  for (int tt = 0; tt < 2; tt++)
    #pragma unroll
    for (int kc = 0; kc < 8; kc++)
      ifrag[tt][kc] = *(const long long*)(iouh8 + (size_t)(((2*wave+tt)*8 + kc)*512) + q*128 + r*8);
  long long cfrag[8];
  #pragma unroll
  for (int kc = 0; kc < 8; kc++)
    cfrag[kc] = *(const long long*)(couh8 + (size_t)((wave*8 + kc)*512) + q*128 + r*8);

  // ---- per-lane output assignments (loop-invariant) ----
  // gate lane (r<8): o_iou = 32w + ((r>>2)&1)*16 + q*4 + (r&3), one sigmoid.
  // update lane (r<4): o_upd = 16w + q*4 + r, one tanh.
  const int o_iou = 32*wave + ((r>>2)&1)*16 + q*4 + (r&3);   // < 512 always
  const int o_upd = 16*wave + q*4 + (r&3);                   // < 256 always
  const float biou_l = iouh_b[o_iou];
  const float invi_l = invrs_iou[o_iou];
  const float bcou_l = couh_b[o_upd];
  const float invc_l = invrs_cou[o_upd];
  float pmax = -1e30f;

  // ---- aggregation mapping: wave's 16-feature slice, lane feature f_agg ----
  const int f_agg = 16*wave + r;
  const int swz_a = SWZ(f_agg);
  const int bfr_base = (f_agg << 9) + (q << 4);   // + kk*64, then ^ swz_a
  // h_new write byte base (update lanes): o_upd*512 + i*2 ^ SWZ(o_upd)
  const int upd_base = (o_upd << 9);
  const int swz_u = SWZ(o_upd);

  // ---- prologue: adjcol f16 for node 0 ----
  if (t < 256){
    const unsigned int w0 = maskw[((size_t)b*NN)*8 + (t>>5)];
    sh_adj[t] = (_Float16)((w0 >> (t&31)) & 1u);
  }
  __syncthreads();   // cover LDS staging + adj(0)

  unsigned int wnext = 0;

  #pragma unroll 1
  for (int i = 0; i < NN; i++){
    const size_t row = (size_t)b*NN + i;

    // masks for NEXT node's adjcol (built in update phase)
    if (t < 256) wnext = maskw[(row+1)*8 + (t>>5)];
    // per-lane OUTX operands (HBM; used ~1000+ cyc later — latency covered)
    const float oxi = (float)OUTX[row*768 + o_iou];
    const float oxc = (float)OUTX[row*768 + 512 + o_upd];
    const float dv  = dinv[row];

    // ---- aggregation: 8 f16 MFMAs; A = adjcol (broadcast), B = H^T frags
    const char* adjc = (const char*)sh_adj + (i&1)*512;
    float4v agg = (float4v){0.f,0.f,0.f,0.f};
    #pragma unroll
    for (int kk = 0; kk < 8; kk++){
      const half8v af = *(const half8v*)(adjc + kk*64 + (q<<4));
      const half8v bf = *(const half8v*)(smem + ((bfr_base + kk*64) ^ swz_a));
      agg = __builtin_amdgcn_mfma_f32_16x16x32_f16(af, bf, agg, 0, 0, 0);
    }
    // every lane holds x_parent[f_agg] (rows replicated); scale and publish
    const float xp = agg[0] * dv;
    if (q == 0)      sh_xp32[f_agg] = xp;
    else if (q == 1) sh_xp8[f_agg] = enc8(xp * 16.f);
    __syncthreads();                                    // B2

    // ---- iou matvec via fp8 MFMA (A-frags in regs) + fused gates ----
    {
      float4v iacc[2];
      iacc[0] = (float4v){0.f,0.f,0.f,0.f};
      iacc[1] = iacc[0];
      #pragma unroll
      for (int kc = 0; kc < 8; kc++){
        const long long bfr = *(const long long*)(sh_xp8 + kc*32 + q*8);
        iacc[0] = mfma_fp8(ifrag[0][kc], bfr, iacc[0]);
        iacc[1] = mfma_fp8(ifrag[1][kc], bfr, iacc[1]);
      }
      if (r < 8){
        // select this lane's output value from the replicated accumulators
        const float4v ia = (r < 4) ? iacc[0] : iacc[1];
        const int rr = r & 3;
        const float v01 = (rr == 0) ? ia[0] : ia[1];
        const float v23 = (rr == 2) ? ia[2] : ia[3];
        const float dval = (rr < 2) ? v01 : v23;
        const float iouv = dval*invi_l + oxi + biou_l;
        const float sg = 1.f / (1.f + __expf(-iouv));
        if (o_iou < 256) sh_p8[o_iou] = enc8(sg * sh_xp32[o_iou] * 16.f);
        else             sh_z[o_iou - 256] = sg;
      }
    }
    __syncthreads();                                    // B3

    // ---- cou matvec (A-frags in regs) + lane-split fused update ----
    {
      float4v cacc = (float4v){0.f,0.f,0.f,0.f};
      #pragma unroll
      for (int kc = 0; kc < 8; kc++){
        const long long bfr = *(const long long*)(sh_p8 + kc*32 + q*8);
        cacc = mfma_fp8(cfrag[kc], bfr, cacc);
      }
      if (r < 4){
        const float c01 = (r == 0) ? cacc[0] : cacc[1];
        const float c23 = (r == 2) ? cacc[2] : cacc[3];
        const float cd  = (r < 2) ? c01 : c23;
        const float v   = cd*invc_l + oxc + bcou_l;
        const float hcv = tanhf(v);
        const float z   = sh_z[o_upd];
        const float xpv = sh_xp32[o_upd];
        const float hn  = z*xpv + (1.f - z)*hcv;
        pmax = fmaxf(pmax, hn);
        // H^T[o_upd][i] swizzled b16 write
        *(_Float16*)(smem + ((upd_base + 2*i) ^ swz_u)) = (_Float16)hn;
      }
      // build next node's adjcol (double-buffered)
      if (t < 256)
        sh_adj[((i+1)&1)*256 + t] = (_Float16)((wnext >> (t&31)) & 1u);
    }
    __syncthreads();                                    // B4
  }

  // ---- epilogue: pooled max -> fc ----
  if (r < 4) sh_pm[o_upd] = pmax;
  __syncthreads();
  if (t < 128){
    const int c = t >> 6;   // 0 or 1
    float s = 0.f;
    #pragma unroll
    for (int qq = 0; qq < 4; qq++){
      const int f = (t & 63) + qq*64;
      s += fc_W[c*256 + f] * sh_pm[f];
    }
    #pragma unroll
    for (int off = 32; off > 0; off >>= 1) s += __shfl_xor(s, off, 64);
    if ((t & 63) == 0) out[b*2 + c] = s + fc_b[c];
  }
}

// ---------------------------------------------------------------------------
extern "C" void kernel_launch(void* const* d_in, const int* in_sizes, int n_in,
                              void* d_out, int out_size, void* d_ws, size_t ws_size,
                              hipStream_t stream)
{
  (void)in_sizes; (void)n_in; (void)out_size; (void)ws_size;
  const float* h      = (const float*)d_in[0];
  const float* adj    = (const float*)d_in[1];
  const float* emb_W  = (const float*)d_in[2];
  const float* ioux_W = (const float*)d_in[3];
  const float* ioux_b = (const float*)d_in[4];
  const float* iouh_W = (const float*)d_in[5];
  const float* iouh_b = (const float*)d_in[6];
  const float* coux_W = (const float*)d_in[7];
  const float* coux_b = (const float*)d_in[8];
  const float* couh_W = (const float*)d_in[9];
  const float* couh_b = (const float*)d_in[10];
  const float* fc_W   = (const float*)d_in[11];
  const float* fc_b   = (const float*)d_in[12];
  float* out = (float*)d_out;

  // ---- carve workspace (256B aligned chunks) ----
  size_t off = 0;
  char* base = (char*)d_ws;
  auto carve = [&](size_t bytes)->char* {
    off = (off + 255) & ~(size_t)255;
    char* p = base + off;
    off += bytes;
    return p;
  };
  _Float16* embW16 = (_Float16*)carve((size_t)256*768*2);
  _Float16* Wcat16 = (_Float16*)carve((size_t)768*256*2);
  float*    biascat= (float*)  carve((size_t)768*4);
  unsigned char* iouh8 = (unsigned char*)carve(131072);
  unsigned char* couh8 = (unsigned char*)carve(65536);
  float*    invrs_iou = (float*)carve(512*4);
  float*    invrs_cou = (float*)carve(256*4);
  float*    dinv   = (float*)  carve((size_t)NB*NN*4);
  unsigned int* maskw = (unsigned int*)carve((size_t)NB*NN*8*4 + 64); // +pad for prefetch
  _Float16* Hc     = (_Float16*)carve((size_t)NB*NN*FOUT*2);       // h_e
  _Float16* OUTX   = (_Float16*)carve((size_t)NB*NN*768*2);        // [iou_x ; cou_x]

  // raise dynamic LDS cap for the scan kernel (idempotent, non-stream op)
  hipFuncSetAttribute((const void*)scan_kernel,
                      hipFuncAttributeMaxDynamicSharedMemorySize, SCAN_LDS);

  // 1) f16 weight conversion for x-side GEMMs
  prep_kernel<<<dim3(1539), dim3(256), 0, stream>>>(
      emb_W, ioux_W, ioux_b, coux_W, coux_b, embW16, Wcat16, biascat);

  // 2) fp8 quantization of recurrent weights (swizzled for MFMA frags)
  quant_kernel<<<dim3(768), dim3(256), 0, stream>>>(
      iouh_W, couh_W, iouh8, couh8, invrs_iou, invrs_cou);

  // 3) degrees + adjacency column bitmasks
  degmask_kernel<<<dim3(NB), dim3(256), 0, stream>>>(adj, maskw, dinv);

  // 4) h_e = h @ emb_W^T
  gemm16_kernel<1><<<dim3(256, 4), dim3(256), 0, stream>>>(
      (const void*)h, embW16, Hc, nullptr, NB*NN, FOUT, FIN, FOUT);

  // 5) [iou_x ; cou_x] = h_e @ Wcat^T + biascat
  gemm16_kernel<0><<<dim3(256, 12), dim3(256), 0, stream>>>(
      (const void*)Hc, Wcat16, OUTX, biascat, NB*NN, 768, FOUT, 768);

  // 6) sequential tree scan (1024 threads; H^T in LDS, weights in VGPRs)
  scan_kernel<<<dim3(NB), dim3(1024), SCAN_LDS, stream>>>(
      Hc, OUTX, iouh8, couh8, invrs_iou, invrs_cou, dinv, maskw,
      iouh_b, couh_b, fc_W, fc_b, out);
}